// Round 1
// baseline (264.609 us; speedup 1.0000x reference)
//
#include <hip/hip_runtime.h>
#include <math.h>

#ifndef M_PI
#define M_PI 3.14159265358979323846
#endif

namespace {
constexpr int B = 4;
constexpr int L = 2048;
constexpr int D = 64;
constexpr int H = 4;
constexpr int NBIN = 1024;
constexpr int CAPC = 1024;   // candidate-bin capacity (typ ~4 used)
constexpr int CAPK = 768;    // kept-list capacity per head (typ ~412 used)
constexpr int OUTW = D + H * D;  // 320
}

__global__ __launch_bounds__(256) void posatt_kernel(
    const float* __restrict__ mesh,    // (B, L, 2)
    const float* __restrict__ inputs,  // (B, L, D)
    const float* __restrict__ lmda,    // (H)
    float* __restrict__ out)           // (B, L, OUTW)
{
    __shared__ float    s_dist[L];          // 8 KB
    __shared__ unsigned s_cum[NBIN];        // 4 KB (hist, then inclusive cumsum)
    __shared__ float    s_cand[CAPC];       // 4 KB
    __shared__ uint2    s_pair[H][CAPK];    // 24 KB: (j*D, bitcast(w))
    __shared__ unsigned s_ccnt;
    __shared__ int      s_b409, s_b410;
    __shared__ unsigned s_base;
    __shared__ float    s_d409, s_d410;
    __shared__ float    s_scale[H];
    __shared__ float    s_thresh[H];
    __shared__ unsigned s_wtot[4];

    const int tid  = threadIdx.x;
    const int lane = tid & 63;
    const int wave = tid >> 6;
    const int row  = blockIdx.x;       // b*L + n
    const int b    = row >> 11;
    const int n    = row & (L - 1);

    const float2* meshb = reinterpret_cast<const float2*>(mesh) + (size_t)b * L;
    const float2 me = meshb[n];

    for (int i = tid; i < NBIN; i += 256) s_cum[i] = 0u;
    if (tid == 0) s_ccnt = 0u;
    __syncthreads();

    // ---- stage 1: pairwise squared distances (exact rn ops, no contraction) + histogram
    float myd[8];
    #pragma unroll
    for (int k = 0; k < 8; ++k) {
        const int j = tid + (k << 8);
        const float2 mj = meshb[j];
        const float dx = __fsub_rn(me.x, mj.x);
        const float dy = __fsub_rn(me.y, mj.y);
        const float d  = __fadd_rn(__fmul_rn(dx, dx), __fmul_rn(dy, dy));
        myd[k] = d;
        s_dist[j] = d;
        int bin = (int)(d * 512.0f);           // monotone binning over [0,2)
        bin = bin < NBIN - 1 ? bin : NBIN - 1;
        atomicAdd(&s_cum[bin], 1u);
    }
    __syncthreads();

    // ---- stage 2: block inclusive scan over the 1024 bins (4 bins/thread)
    const unsigned c0 = s_cum[tid * 4 + 0];
    const unsigned c1 = s_cum[tid * 4 + 1];
    const unsigned c2 = s_cum[tid * 4 + 2];
    const unsigned c3 = s_cum[tid * 4 + 3];
    const unsigned i0 = c0, i1 = i0 + c1, i2 = i1 + c2, i3 = i2 + c3;
    const unsigned tot = i3;
    unsigned sc = tot;
    #pragma unroll
    for (int off = 1; off < 64; off <<= 1) {
        const unsigned u = __shfl_up(sc, off);
        if (lane >= off) sc += u;
    }
    if (lane == 63) s_wtot[wave] = sc;
    __syncthreads();
    unsigned wb = 0;
    for (int w = 0; w < wave; ++w) wb += s_wtot[w];
    const unsigned ebase = wb + sc - tot;      // exclusive base for this thread's bins
    s_cum[tid * 4 + 0] = ebase + i0;
    s_cum[tid * 4 + 1] = ebase + i1;
    s_cum[tid * 4 + 2] = ebase + i2;
    s_cum[tid * 4 + 3] = ebase + i3;
    __syncthreads();

    // ---- locate bins holding ranks 409 and 410 (unique crossing each)
    #pragma unroll
    for (int i = 0; i < 4; ++i) {
        const int bin = tid * 4 + i;
        const unsigned cumv = s_cum[bin];
        const unsigned prev = (bin == 0) ? 0u : s_cum[bin - 1];
        if (cumv > 409u && prev <= 409u) { s_b409 = bin; s_base = prev; }
        if (cumv > 410u && prev <= 410u) { s_b410 = bin; }
    }
    __syncthreads();

    const int b409 = s_b409;
    const int b410 = s_b410;
    const unsigned base = s_base;

    // ---- stage 3: gather candidates from bins [b409, b410]
    #pragma unroll
    for (int k = 0; k < 8; ++k) {
        const float d = myd[k];
        int bin = (int)(d * 512.0f);
        bin = bin < NBIN - 1 ? bin : NBIN - 1;
        if (bin >= b409 && bin <= b410) {
            const unsigned p = atomicAdd(&s_ccnt, 1u);
            if (p < (unsigned)CAPC) s_cand[p] = d;
        }
    }
    __syncthreads();

    // ---- stage 4: wave0 exact-selects d409/d410; wave1 computes head scales
    if (wave == 0) {
        const int m = (int)min(s_ccnt, (unsigned)CAPC);
        const int k409 = 409 - (int)base;
        const int k410 = 410 - (int)base;
        for (int cc = 0; cc < m; cc += 64) {
            const int ci = cc + lane;
            const float v = (ci < m) ? s_cand[ci] : 0.0f;
            int lt = 0, le = 0;
            for (int i = 0; i < m; ++i) {
                const float u = s_cand[i];
                lt += (u < v) ? 1 : 0;
                le += (u <= v) ? 1 : 0;
            }
            if (ci < m) {
                if (lt <= k409 && k409 < le) s_d409 = v;
                if (lt <= k410 && k410 < le) s_d410 = v;
            }
        }
    } else if (wave == 1 && lane < H) {
        const double lam = (double)lmda[lane];
        const float  C   = (float)(0.25 * M_PI * (1.0 - 1e-07));
        const float  s1  = (float)sin(lam);
        const float  arg = __fmul_rn(C, __fadd_rn(1.0f, s1));
        s_scale[lane] = (float)tan((double)arg);
    }
    __syncthreads();

    // ---- per-head threshold, replicating jnp.quantile's lerp in fp32
    if (tid < H) {
        const float scl  = s_scale[tid];
        const float s409 = __fmul_rn(s_d409, scl);
        const float s410 = __fmul_rn(s_d410, scl);
        const float pos  = 0.2f * 2047.0f;     // fp32-folded: 409.39999...
        const float g    = pos - 409.0f;       // high weight
        const float lw   = 1.0f - g;           // low weight
        s_thresh[tid] = __fadd_rn(__fmul_rn(s409, lw), __fmul_rn(s410, g));
    }
    __syncthreads();

    // ---- stage 5: per-wave (= per-head) ballot compaction of kept (offset, weight)
    const int h = wave;
    const float scl = s_scale[h];
    const float th  = s_thresh[h];
    int cnt = 0;
    float wsum = 0.0f;
    for (int j0 = 0; j0 < L; j0 += 64) {
        const int j = j0 + lane;
        const float scaled = __fmul_rn(s_dist[j], scl);
        const bool kept = (scaled <= th);
        const unsigned long long mask = __ballot(kept);
        if (kept) {
            const int pos = cnt + __popcll(mask & ((1ull << lane) - 1ull));
            const float w = expf(-scaled);
            if (pos < CAPK) s_pair[h][pos] = make_uint2((unsigned)(j * D), __float_as_uint(w));
            wsum += w;
        }
        cnt += (int)__popcll(mask);
    }
    cnt = cnt < CAPK ? cnt : CAPK;
    const int pad = (8 - (cnt & 7)) & 7;       // pad to multiple of 8 (w=0 entries)
    if (lane < pad) s_pair[h][cnt + lane] = make_uint2(0u, 0u);
    const int cntp = cnt + pad;
    #pragma unroll
    for (int off = 32; off > 0; off >>= 1) wsum += __shfl_xor(wsum, off);
    const float inv = 1.0f / wsum;

    // ---- stage 6: aggregation — 4 kept rows per wave-iter, float4 per lane
    const float* inpb = inputs + (size_t)b * L * D;
    const int grp = lane >> 4;   // which of 4 kept rows this lane handles
    const int q   = lane & 15;   // which d-quad
    float ax = 0.0f, ay = 0.0f, az = 0.0f, aw = 0.0f;
    #pragma unroll 2
    for (int c = 0; c < cntp; c += 4) {
        const uint2 p = s_pair[h][c + grp];
        const float w = __uint_as_float(p.y);
        const float4 x = *reinterpret_cast<const float4*>(inpb + p.x + (q << 2));
        ax += w * x.x; ay += w * x.y; az += w * x.z; aw += w * x.w;
    }
    #pragma unroll
    for (int m = 16; m <= 32; m <<= 1) {
        ax += __shfl_xor(ax, m);
        ay += __shfl_xor(ay, m);
        az += __shfl_xor(az, m);
        aw += __shfl_xor(aw, m);
    }
    float* outr = out + (size_t)row * OUTW;
    if (grp == 0) {
        float4 r;
        r.x = ax * inv; r.y = ay * inv; r.z = az * inv; r.w = aw * inv;
        *reinterpret_cast<float4*>(outr + D + h * D + (q << 2)) = r;
    }
    // ---- passthrough of inputs into out[:, :, 0:64]
    if (wave == 0) {
        outr[lane] = inpb[n * D + lane];
    }
}

extern "C" void kernel_launch(void* const* d_in, const int* in_sizes, int n_in,
                              void* d_out, int out_size, void* d_ws, size_t ws_size,
                              hipStream_t stream) {
    const float* mesh   = (const float*)d_in[0];
    const float* inputs = (const float*)d_in[1];
    const float* lmda   = (const float*)d_in[2];
    float* out = (float*)d_out;
    (void)in_sizes; (void)n_in; (void)out_size; (void)d_ws; (void)ws_size;
    hipLaunchKernelGGL(posatt_kernel, dim3(B * L), dim3(256), 0, stream,
                       mesh, inputs, lmda, out);
}

// Round 2
// 158.844 us; speedup vs baseline: 1.6658x; 1.6658x over previous
//
#include <hip/hip_runtime.h>
#include <math.h>

#ifndef M_PI
#define M_PI 3.14159265358979323846
#endif

namespace {
constexpr int B = 4;
constexpr int L = 2048;
constexpr int D = 64;
constexpr int H = 4;
constexpr int NBIN = 512;       // histogram bins over d2 in [0,2)
constexpr int CAPC = 256;       // candidate-bin capacity (typ ~25-50 used)
constexpr int CAPK = 544;       // shared kept-list capacity (typ ~412 used)
constexpr int OUTW = D + H * D; // 320
}

__global__ __launch_bounds__(256, 6) void posatt_kernel(
    const float* __restrict__ mesh,    // (B, L, 2)
    const float* __restrict__ inputs,  // (B, L, D)
    const float* __restrict__ lmda,    // (H)
    float* __restrict__ out)           // (B, L, OUTW)
{
    __shared__ float    s_dist[L];           // 8 KB
    __shared__ unsigned s_cum[NBIN];         // 2 KB (hist -> inclusive cumsum)
    __shared__ float    s_cand[CAPC];        // 1 KB
    __shared__ unsigned s_j[CAPK];           // 2.1 KB  (j*D)
    __shared__ float4   s_w[CAPK];           // 8.5 KB  (w per head)
    __shared__ float4   s_red[4][H][16];     // 4 KB    (per-wave partials)
    __shared__ float    s_wsumw[4][H];       // 64 B
    __shared__ unsigned s_ccnt, s_kcnt;
    __shared__ int      s_b409, s_b410;
    __shared__ unsigned s_base;
    __shared__ float    s_d409, s_d410;
    __shared__ float    s_scale[H];
    __shared__ float    s_thresh[H];
    __shared__ unsigned s_wtot[4];

    const int tid  = threadIdx.x;
    const int lane = tid & 63;
    const int wave = tid >> 6;
    const int row  = blockIdx.x;       // b*L + n
    const int b    = row >> 11;
    const int n    = row & (L - 1);

    const float2* meshb = reinterpret_cast<const float2*>(mesh) + (size_t)b * L;
    const float2 me = meshb[n];

    for (int i = tid; i < NBIN; i += 256) s_cum[i] = 0u;
    if (tid == 0) { s_ccnt = 0u; s_kcnt = 0u; }
    __syncthreads();

    // ---- stage 1: pairwise squared distances (exact rn ops) + histogram
    float myd[8];
    #pragma unroll
    for (int k = 0; k < 8; ++k) {
        const int j = tid + (k << 8);
        const float2 mj = meshb[j];
        const float dx = __fsub_rn(me.x, mj.x);
        const float dy = __fsub_rn(me.y, mj.y);
        const float d  = __fadd_rn(__fmul_rn(dx, dx), __fmul_rn(dy, dy));
        myd[k] = d;
        s_dist[j] = d;
        int bin = (int)(d * 256.0f);           // monotone binning over [0,2)
        bin = bin < NBIN - 1 ? bin : NBIN - 1;
        atomicAdd(&s_cum[bin], 1u);
    }
    __syncthreads();

    // ---- stage 2: block inclusive scan over 512 bins (2 bins/thread)
    const unsigned c0 = s_cum[tid * 2 + 0];
    const unsigned c1 = s_cum[tid * 2 + 1];
    const unsigned i0 = c0, i1 = i0 + c1;
    const unsigned tot = i1;
    unsigned sc = tot;
    #pragma unroll
    for (int off = 1; off < 64; off <<= 1) {
        const unsigned u = __shfl_up(sc, off);
        if (lane >= off) sc += u;
    }
    if (lane == 63) s_wtot[wave] = sc;
    __syncthreads();
    unsigned wb = 0;
    for (int w = 0; w < wave; ++w) wb += s_wtot[w];
    const unsigned ebase = wb + sc - tot;      // exclusive base for this thread's bins
    s_cum[tid * 2 + 0] = ebase + i0;
    s_cum[tid * 2 + 1] = ebase + i1;
    __syncthreads();

    // ---- locate bins holding ranks 409 and 410
    #pragma unroll
    for (int i = 0; i < 2; ++i) {
        const int bin = tid * 2 + i;
        const unsigned cumv = s_cum[bin];
        const unsigned prev = (bin == 0) ? 0u : s_cum[bin - 1];
        if (cumv > 409u && prev <= 409u) { s_b409 = bin; s_base = prev; }
        if (cumv > 410u && prev <= 410u) { s_b410 = bin; }
    }
    __syncthreads();

    const int b409 = s_b409;
    const int b410 = s_b410;
    const unsigned base = s_base;

    // ---- stage 3: gather candidates from bins [b409, b410]
    #pragma unroll
    for (int k = 0; k < 8; ++k) {
        const float d = myd[k];
        int bin = (int)(d * 256.0f);
        bin = bin < NBIN - 1 ? bin : NBIN - 1;
        if (bin >= b409 && bin <= b410) {
            const unsigned p = atomicAdd(&s_ccnt, 1u);
            if (p < (unsigned)CAPC) s_cand[p] = d;
        }
    }
    __syncthreads();

    // ---- stage 4: wave0 exact-selects d409/d410; wave1 computes head scales
    if (wave == 0) {
        const int m = (int)min(s_ccnt, (unsigned)CAPC);
        const int k409 = 409 - (int)base;
        const int k410 = 410 - (int)base;
        for (int cc = 0; cc < m; cc += 64) {
            const int ci = cc + lane;
            const float v = (ci < m) ? s_cand[ci] : 0.0f;
            int lt = 0, le = 0;
            for (int i = 0; i < m; ++i) {
                const float u = s_cand[i];
                lt += (u < v) ? 1 : 0;
                le += (u <= v) ? 1 : 0;
            }
            if (ci < m) {
                if (lt <= k409 && k409 < le) s_d409 = v;
                if (lt <= k410 && k410 < le) s_d410 = v;
            }
        }
    } else if (wave == 1 && lane < H) {
        const double lam = (double)lmda[lane];
        const float  C   = (float)(0.25 * M_PI * (1.0 - 1e-07));
        const float  s1  = (float)sin(lam);
        const float  arg = __fmul_rn(C, __fadd_rn(1.0f, s1));
        s_scale[lane] = (float)tan((double)arg);
    }
    __syncthreads();

    // ---- per-head threshold, replicating jnp.quantile's lerp in fp32
    if (tid < H) {
        const float scl  = s_scale[tid];
        const float s409 = __fmul_rn(s_d409, scl);
        const float s410 = __fmul_rn(s_d410, scl);
        const float pos  = 0.2f * 2047.0f;     // fp32-folded: 409.39999...
        const float g    = pos - 409.0f;       // high weight
        const float lw   = 1.0f - g;           // low weight
        s_thresh[tid] = __fadd_rn(__fmul_rn(s409, lw), __fmul_rn(s410, g));
    }
    __syncthreads();

    // ---- stage 5: SHARED compaction — kept-by-any-head list with 4 weights
    const float sc0 = s_scale[0], sc1 = s_scale[1], sc2 = s_scale[2], sc3 = s_scale[3];
    const float th0 = s_thresh[0], th1 = s_thresh[1], th2 = s_thresh[2], th3 = s_thresh[3];
    float lw0 = 0.0f, lw1 = 0.0f, lw2 = 0.0f, lw3 = 0.0f;
    for (int jj = wave * 512; jj < wave * 512 + 512; jj += 64) {
        const int j = jj + lane;
        const float d  = s_dist[j];
        const float x0 = __fmul_rn(d, sc0);
        const float x1 = __fmul_rn(d, sc1);
        const float x2 = __fmul_rn(d, sc2);
        const float x3 = __fmul_rn(d, sc3);
        const bool k0 = (x0 <= th0), k1 = (x1 <= th1), k2 = (x2 <= th2), k3 = (x3 <= th3);
        const bool any = k0 | k1 | k2 | k3;
        const unsigned long long mask = __ballot(any);
        const int nk = (int)__popcll(mask);
        unsigned bse = 0u;
        if (lane == 0 && nk) bse = atomicAdd(&s_kcnt, (unsigned)nk);
        bse = (unsigned)__shfl((int)bse, 0);
        if (any) {
            const int pos = (int)bse + (int)__popcll(mask & ((1ull << lane) - 1ull));
            const float w0 = k0 ? expf(-x0) : 0.0f;
            const float w1 = k1 ? expf(-x1) : 0.0f;
            const float w2 = k2 ? expf(-x2) : 0.0f;
            const float w3 = k3 ? expf(-x3) : 0.0f;
            if (pos < 512) {
                s_j[pos] = (unsigned)(j * D);
                s_w[pos] = make_float4(w0, w1, w2, w3);
            }
            lw0 += w0; lw1 += w1; lw2 += w2; lw3 += w3;
        }
    }
    #pragma unroll
    for (int off = 32; off > 0; off >>= 1) {
        lw0 += __shfl_xor(lw0, off);
        lw1 += __shfl_xor(lw1, off);
        lw2 += __shfl_xor(lw2, off);
        lw3 += __shfl_xor(lw3, off);
    }
    if (lane == 0) {
        s_wsumw[wave][0] = lw0; s_wsumw[wave][1] = lw1;
        s_wsumw[wave][2] = lw2; s_wsumw[wave][3] = lw3;
    }
    __syncthreads();

    // ---- pad kept list to multiple of 16 with zero-weight entries
    const int cnt  = (int)min(s_kcnt, 512u);
    const int cntp = (cnt + 15) & ~15;
    if (tid < cntp - cnt) {
        s_j[cnt + tid] = 0u;
        s_w[cnt + tid] = make_float4(0.0f, 0.0f, 0.0f, 0.0f);
    }
    __syncthreads();

    // ---- stage 6: aggregation — waves split entries; each x-load feeds 4 heads
    const float* inpb = inputs + (size_t)b * L * D;
    const int grp = lane >> 4;   // which of this wave's 4 entries per iter
    const int q   = lane & 15;   // which d-quad
    float4 a0 = make_float4(0,0,0,0), a1 = a0, a2 = a0, a3 = a0;
    for (int c = wave * 4 + grp; c < cntp; c += 16) {
        const unsigned joff = s_j[c];
        const float4 w = s_w[c];
        const float4 x = *reinterpret_cast<const float4*>(inpb + joff + (q << 2));
        a0.x += w.x * x.x; a0.y += w.x * x.y; a0.z += w.x * x.z; a0.w += w.x * x.w;
        a1.x += w.y * x.x; a1.y += w.y * x.y; a1.z += w.y * x.z; a1.w += w.y * x.w;
        a2.x += w.z * x.x; a2.y += w.z * x.y; a2.z += w.z * x.z; a2.w += w.z * x.w;
        a3.x += w.w * x.x; a3.y += w.w * x.y; a3.z += w.w * x.z; a3.w += w.w * x.w;
    }
    #pragma unroll
    for (int m = 16; m <= 32; m <<= 1) {
        a0.x += __shfl_xor(a0.x, m); a0.y += __shfl_xor(a0.y, m);
        a0.z += __shfl_xor(a0.z, m); a0.w += __shfl_xor(a0.w, m);
        a1.x += __shfl_xor(a1.x, m); a1.y += __shfl_xor(a1.y, m);
        a1.z += __shfl_xor(a1.z, m); a1.w += __shfl_xor(a1.w, m);
        a2.x += __shfl_xor(a2.x, m); a2.y += __shfl_xor(a2.y, m);
        a2.z += __shfl_xor(a2.z, m); a2.w += __shfl_xor(a2.w, m);
        a3.x += __shfl_xor(a3.x, m); a3.y += __shfl_xor(a3.y, m);
        a3.z += __shfl_xor(a3.z, m); a3.w += __shfl_xor(a3.w, m);
    }
    if (lane < 16) {
        s_red[wave][0][lane] = a0;
        s_red[wave][1][lane] = a1;
        s_red[wave][2][lane] = a2;
        s_red[wave][3][lane] = a3;
    }
    __syncthreads();

    // ---- epilogue: wave h sums partials for head h, normalizes, stores
    float* outr = out + (size_t)row * OUTW;
    const int h = wave;
    const float wsum = s_wsumw[0][h] + s_wsumw[1][h] + s_wsumw[2][h] + s_wsumw[3][h];
    const float inv = 1.0f / wsum;
    if (lane < 16) {
        const float4 r0 = s_red[0][h][lane];
        const float4 r1 = s_red[1][h][lane];
        const float4 r2 = s_red[2][h][lane];
        const float4 r3 = s_red[3][h][lane];
        float4 r;
        r.x = (r0.x + r1.x + r2.x + r3.x) * inv;
        r.y = (r0.y + r1.y + r2.y + r3.y) * inv;
        r.z = (r0.z + r1.z + r2.z + r3.z) * inv;
        r.w = (r0.w + r1.w + r2.w + r3.w) * inv;
        *reinterpret_cast<float4*>(outr + D + h * D + (lane << 2)) = r;
    }
    // ---- passthrough of inputs into out[:, :, 0:64]
    if (wave == 0) {
        outr[lane] = inpb[n * D + lane];
    }
}

extern "C" void kernel_launch(void* const* d_in, const int* in_sizes, int n_in,
                              void* d_out, int out_size, void* d_ws, size_t ws_size,
                              hipStream_t stream) {
    const float* mesh   = (const float*)d_in[0];
    const float* inputs = (const float*)d_in[1];
    const float* lmda   = (const float*)d_in[2];
    float* out = (float*)d_out;
    (void)in_sizes; (void)n_in; (void)out_size; (void)d_ws; (void)ws_size;
    hipLaunchKernelGGL(posatt_kernel, dim3(B * L), dim3(256), 0, stream,
                       mesh, inputs, lmda, out);
}